// Round 7
// baseline (565.718 us; speedup 1.0000x reference)
//
#include <hip/hip_runtime.h>

// SNN: 3-layer LIF, B=256, T=32, H=1024, IN=2312, OUT=10.
// Round-7: f16 2-plane scaled split + BK=64 K-tiles. Evidence: rounds with 96
// MFMA/wave per barrier-pair run 42% MfmaUtil (r2/r3), rounds with 48 run ~13%
// (r4/r6) — per-tile stall is ~fixed, so double MFMA per barrier and halve the
// barrier count. Loop skeleton = round 3's exactly (prefetch between commit
// and barrier [B] — only placement measured at 42%). LDS 64KB via XOR chunk
// swizzle (no pad), 2 blocks/CU, launch_bounds(256,2) (proven no-spill).
//   x = x0 + x1s*2^-12 ; W*SC = w0 + w1s*2^-12 (SC: 64 W1, 32 W2)
//   acc0 = sum x0*w0 ; acc1 = sum (x0*w1s + x1s*w0)
//   C = acc0/SC + acc1/(SC*4096) + bias  (dropped term ~2^-22 rel; absmax 0.0
//   for this scheme in rounds 4-6)

#define TB 256
#define TT 32
#define TH 1024
#define TIN 2312
#define TOUT 10
#define TM (TT * TB)   // 8192 rows = (t,b)
#define KP1 2368       // TIN padded to multiple of 64 (37*64)

typedef _Float16 f16_t;
typedef f16_t f16x8 __attribute__((ext_vector_type(8)));
typedef f16_t f16x4 __attribute__((ext_vector_type(4)));
typedef float floatx4 __attribute__((ext_vector_type(4)));

// chunk swizzle: 8-f16 chunk ck of row m lives at slot ck ^ (m&7)
__device__ __forceinline__ int foff(int m, int ck) {
  return m * 64 + ((ck ^ (m & 7)) * 8);
}

// W (rows x K) -> 2 scaled f16 planes (rows x Kp), zero-padded K..Kp.
__global__ __launch_bounds__(256) void split_w(const float* __restrict__ W,
                                               f16_t* __restrict__ P,
                                               long plane, int K, int Kp,
                                               float sc) {
  int k4 = (blockIdx.x * 256 + threadIdx.x) * 4;
  if (k4 >= Kp) return;
  long r = blockIdx.y;
  float4 v = (k4 < K) ? *(const float4*)(W + r * (long)K + k4)
                      : float4{0.f, 0.f, 0.f, 0.f};
  float t[4] = {v.x * sc, v.y * sc, v.z * sc, v.w * sc};
  f16x4 a, b;
  #pragma unroll
  for (int e = 0; e < 4; ++e) {
    f16_t h0 = (f16_t)t[e];
    a[e] = h0;
    b[e] = (f16_t)((t[e] - (float)h0) * 4096.f);
  }
  long o = r * (long)Kp + k4;
  *(f16x4*)(P + o) = a;
  *(f16x4*)(P + plane + o) = b;
}

// C[r][n]: A row element offset = (r>>8)*sT + (r&255)*sB.
// AF32: A fp32 -> split to 2 f16 planes in LDS commit (96 MFMA/wave/tile).
// else: A f16 spikes, exact (64 MFMA/wave/tile).
template <bool AF32>
__global__ __launch_bounds__(256, 2) void snn_gemm(
    const float* __restrict__ Af, const f16_t* __restrict__ Ab,
    long sT, long sB, const f16_t* __restrict__ Bp, long planeB,
    int Kp, int K, int numT, const float* __restrict__ bias,
    float* __restrict__ C, int N, float s0, float s1) {
  constexpr int APL = AF32 ? 2 : 1;
  __shared__ f16_t As[APL][128 * 64];  // 16 KB/plane
  __shared__ f16_t Bs[2][128 * 64];

  const int tid = threadIdx.x;
  const int wave = tid >> 6, lane = tid & 63;
  const int quad = lane >> 4, l16 = lane & 15;
  const int wm = (wave & 1) * 64, wn = (wave >> 1) * 64;
  const long m0 = (long)blockIdx.x * 128;
  const long n0 = (long)blockIdx.y * 128;

  floatx4 acc0[4][4], acc1[4][4];
  #pragma unroll
  for (int i = 0; i < 4; ++i)
    #pragma unroll
    for (int j = 0; j < 4; ++j) {
      acc0[i][j] = (floatx4){0.f, 0.f, 0.f, 0.f};
      acc1[i][j] = (floatx4){0.f, 0.f, 0.f, 0.f};
    }

  // staging: chunk c = p*256+tid (p<4) -> row c>>3, k-chunk c&7 (8 elems)
  float4 xv[4][2];
  f16x8 av[4];
  f16x8 bv[2][4];

  auto prefetch = [&](int kt) {
    const int kb = kt * 64;
    #pragma unroll
    for (int p = 0; p < 4; ++p) {
      const int c = p * 256 + tid;
      const int row = c >> 3;
      const long r = m0 + row;
      const int k0 = kb + (c & 7) * 8;
      if constexpr (AF32) {
        const float* xr = Af + (r >> 8) * sT + (r & 255) * sB + k0;
        const bool in = (k0 + 8 <= K);  // K multiple of 8 -> all-or-nothing
        const float4 z = {0.f, 0.f, 0.f, 0.f};
        xv[p][0] = in ? *(const float4*)xr : z;
        xv[p][1] = in ? *(const float4*)(xr + 4) : z;
      } else {
        av[p] = *(const f16x8*)(Ab + (r >> 8) * sT + (r & 255) * sB + k0);
      }
      #pragma unroll
      for (int q = 0; q < 2; ++q)
        bv[q][p] = *(const f16x8*)(Bp + q * planeB +
                                   (n0 + row) * (long)Kp + k0);
    }
  };

  auto commit = [&]() {
    #pragma unroll
    for (int p = 0; p < 4; ++p) {
      const int c = p * 256 + tid;
      const int off = foff(c >> 3, c & 7);
      if constexpr (AF32) {
        float v[8] = {xv[p][0].x, xv[p][0].y, xv[p][0].z, xv[p][0].w,
                      xv[p][1].x, xv[p][1].y, xv[p][1].z, xv[p][1].w};
        f16x8 h0, h1;
        #pragma unroll
        for (int e = 0; e < 8; ++e) {
          f16_t a = (f16_t)v[e];
          h0[e] = a;
          h1[e] = (f16_t)((v[e] - (float)a) * 4096.f);
        }
        *(f16x8*)(&As[0][off]) = h0;
        *(f16x8*)(&As[1][off]) = h1;
      } else {
        *(f16x8*)(&As[0][off]) = av[p];
      }
      *(f16x8*)(&Bs[0][off]) = bv[0][p];
      *(f16x8*)(&Bs[1][off]) = bv[1][p];
    }
  };

  prefetch(0);
  for (int kt = 0; kt < numT; ++kt) {
    __syncthreads();  // [A] prev tile's frag reads done
    commit();
    const int kn = (kt + 1 < numT) ? kt + 1 : 0;  // harmless reload at end
    prefetch(kn);     // round-3 placement: issue before [B]
    __syncthreads();  // [B] staging visible
    #pragma unroll
    for (int kk = 0; kk < 2; ++kk) {  // two k-32 halves of the 64-tile
      f16x8 a0[4], b0[4], b1[4];
      #pragma unroll
      for (int i = 0; i < 4; ++i)
        a0[i] = *(const f16x8*)(&As[0][foff(wm + i * 16 + l16, kk * 4 + quad)]);
      #pragma unroll
      for (int j = 0; j < 4; ++j) {
        b0[j] = *(const f16x8*)(&Bs[0][foff(wn + j * 16 + l16, kk * 4 + quad)]);
        b1[j] = *(const f16x8*)(&Bs[1][foff(wn + j * 16 + l16, kk * 4 + quad)]);
      }
      #pragma unroll
      for (int i = 0; i < 4; ++i)
        #pragma unroll
        for (int j = 0; j < 4; ++j)
          acc0[i][j] = __builtin_amdgcn_mfma_f32_16x16x32_f16(
              a0[i], b0[j], acc0[i][j], 0, 0, 0);
      #pragma unroll
      for (int i = 0; i < 4; ++i)
        #pragma unroll
        for (int j = 0; j < 4; ++j)
          acc1[i][j] = __builtin_amdgcn_mfma_f32_16x16x32_f16(
              a0[i], b1[j], acc1[i][j], 0, 0, 0);
      if constexpr (AF32) {
        #pragma unroll
        for (int i = 0; i < 4; ++i) {
          f16x8 a1 =
              *(const f16x8*)(&As[1][foff(wm + i * 16 + l16, kk * 4 + quad)]);
          #pragma unroll
          for (int j = 0; j < 4; ++j)
            acc1[i][j] = __builtin_amdgcn_mfma_f32_16x16x32_f16(
                a1, b0[j], acc1[i][j], 0, 0, 0);
        }
      }
    }
  }

  // epilogue: C/D layout col=lane&15, row=quad*4+reg
  #pragma unroll
  for (int j = 0; j < 4; ++j) {
    const long col = n0 + wn + j * 16 + l16;
    const float bvv = bias[col];
    #pragma unroll
    for (int i = 0; i < 4; ++i) {
      const long row0 = m0 + wm + i * 16 + quad * 4;
      #pragma unroll
      for (int g = 0; g < 4; ++g)
        C[(row0 + g) * (long)N + col] =
            acc0[i][j][g] * s0 + acc1[i][j][g] * s1 + bvv;
    }
  }
}

// LIF scan: fp32 currents in, f16 spikes {0,1} out (exact).
__global__ __launch_bounds__(256) void lif_scan_f16(const float* __restrict__ I,
                                                    f16_t* __restrict__ S) {
  int idx = blockIdx.x * 256 + threadIdx.x;
  float v = 0.f, cur = 0.f;
  #pragma unroll
  for (int t = 0; t < TT; ++t) {
    float inp = I[(long)t * (TB * TH) + idx];
    float vd = fmaf(0.05f, cur - v, v);
    float id = cur - 0.2f * cur;
    float s = (vd > 1.0f) ? 1.0f : 0.f;
    v = (1.0f - s) * vd;
    cur = id + inp;
    S[(long)t * (TB * TH) + idx] = (f16_t)s;
  }
}

// GEMM3: one wave per row; I3[r][o] = S2[r][:] . Wout[o][:] + bout[o]
__global__ __launch_bounds__(256) void gemm3_kernel(
    const f16_t* __restrict__ S2, const float* __restrict__ Wout,
    const float* __restrict__ bout, float* __restrict__ I3) {
  int wv = (blockIdx.x * 256 + threadIdx.x) >> 6;
  int lane = threadIdx.x & 63;
  if (wv >= TM) return;
  const f16_t* srow = S2 + (long)wv * TH;
  float acc[TOUT];
  #pragma unroll
  for (int o = 0; o < TOUT; ++o) acc[o] = 0.f;
  const int k0 = lane * 16;  // 64 lanes x 16 = 1024 = TH
  f16x8 sa = *(const f16x8*)(srow + k0);
  f16x8 sb = *(const f16x8*)(srow + k0 + 8);
  #pragma unroll
  for (int e = 0; e < 8; ++e) {
    float u = (float)sa[e], w = (float)sb[e];
    #pragma unroll
    for (int o = 0; o < TOUT; ++o) {
      acc[o] = fmaf(u, Wout[o * TH + k0 + e], acc[o]);
      acc[o] = fmaf(w, Wout[o * TH + k0 + 8 + e], acc[o]);
    }
  }
  #pragma unroll
  for (int off = 32; off > 0; off >>= 1)
    #pragma unroll
    for (int o = 0; o < TOUT; ++o) acc[o] += __shfl_down(acc[o], off, 64);
  if (lane == 0) {
    #pragma unroll
    for (int o = 0; o < TOUT; ++o) I3[(long)wv * TOUT + o] = acc[o] + bout[o];
  }
}

__global__ __launch_bounds__(256) void scan_out(const float* __restrict__ I3,
                                                float* __restrict__ out) {
  int idx = blockIdx.x * blockDim.x + threadIdx.x;
  if (idx >= TB * TOUT) return;
  float v = 0.f, cur = 0.f, cnt = 0.f;
  #pragma unroll
  for (int t = 0; t < TT; ++t) {
    float inp = I3[(long)t * (TB * TOUT) + idx];
    float vd = fmaf(0.05f, cur - v, v);
    float id = cur - 0.2f * cur;
    float s = (vd > 1.0f) ? 1.0f : 0.f;
    v = (1.0f - s) * vd;
    cur = id + inp;
    cnt += s;
  }
  out[idx] = cnt;
}

extern "C" void kernel_launch(void* const* d_in, const int* in_sizes, int n_in,
                              void* d_out, int out_size, void* d_ws,
                              size_t ws_size, hipStream_t stream) {
  const float* x    = (const float*)d_in[0];  // (256,32,2312)
  const float* W1   = (const float*)d_in[1];  // (1024,2312)
  const float* b1   = (const float*)d_in[2];
  const float* W2   = (const float*)d_in[3];  // (1024,1024)
  const float* b2   = (const float*)d_in[4];
  const float* Wout = (const float*)d_in[5];  // (10,1024)
  const float* bout = (const float*)d_in[6];

  // ws: W1p 9.70MB | W2p 4.19MB | bufI 33.55MB | S 16.78MB | buf3 0.33MB
  f16_t* W1p  = (f16_t*)d_ws;
  f16_t* W2p  = W1p + 2L * TH * KP1;
  float* bufI = (float*)(W2p + 2L * TH * TH);
  f16_t* S    = (f16_t*)(bufI + (long)TM * TH);
  float* buf3 = (float*)(S + (long)TM * TH);

  split_w<<<dim3((KP1 / 4 + 255) / 256, TH), 256, 0, stream>>>(
      W1, W1p, (long)TH * KP1, TIN, KP1, 64.f);
  split_w<<<dim3(1, TH), 256, 0, stream>>>(
      W2, W2p, (long)TH * TH, TH, TH, 32.f);

  // GEMM1: row r=(t,b): x offset = (r&255)*(32*2312) + (r>>8)*2312
  snn_gemm<true><<<dim3(TM / 128, TH / 128), 256, 0, stream>>>(
      x, nullptr, (long)TIN, (long)TT * TIN, W1p, (long)TH * KP1, KP1, TIN,
      KP1 / 64, b1, bufI, TH, 1.f / 64.f, 1.f / 262144.f);

  lif_scan_f16<<<(TB * TH) / 256, 256, 0, stream>>>(bufI, S);

  // GEMM2: S row-major [8192][1024]
  snn_gemm<false><<<dim3(TM / 128, TH / 128), 256, 0, stream>>>(
      nullptr, S, (long)TB * TH, (long)TH, W2p, (long)TH * TH, TH, TH,
      TH / 64, b2, bufI, TH, 1.f / 32.f, 1.f / 131072.f);

  lif_scan_f16<<<(TB * TH) / 256, 256, 0, stream>>>(bufI, S);

  gemm3_kernel<<<(TM * 64) / 256, 256, 0, stream>>>(S, Wout, bout, buf3);

  scan_out<<<(TB * TOUT + 255) / 256, 256, 0, stream>>>(buf3, (float*)d_out);
}

// Round 8
// 532.109 us; speedup vs baseline: 1.0632x; 1.0632x over previous
//
#include <hip/hip_runtime.h>

// SNN: 3-layer LIF, B=256, T=32, H=1024, IN=2312, OUT=10.
// Round-8: SINGLE-VARIABLE EXPERIMENT. Source = round-6 (f16 2-plane scaled
// split, BK=32, LDW=36, reg staging, launch_bounds(256,2)) with exactly one
// change: prefetch issued BETWEEN commit and barrier [B] (round-3's position,
// the only placement ever measured at 42% MfmaUtil). Controls: r3 (bf16,
// this placement, 42%) and r6 (f16, after-[B], 12.8%). Outcome attributes the
// f16 slowdown to either prefetch placement or the dual-accumulator scheme.
//   x = x0 + x1s*2^-12 ; W*SC = w0 + w1s*2^-12 (SC: 64 W1, 32 W2)
//   acc0 = sum x0*w0 ; acc1 = sum (x0*w1s + x1s*w0)
//   C = acc0/SC + acc1/(SC*4096) + bias  (absmax 0.0 in r4-r7)

#define TB 256
#define TT 32
#define TH 1024
#define TIN 2312
#define TOUT 10
#define TM (TT * TB)   // 8192 rows = (t,b)
#define KP1 2368       // TIN padded to multiple of 32

typedef _Float16 f16_t;
typedef f16_t f16x8 __attribute__((ext_vector_type(8)));
typedef f16_t f16x4 __attribute__((ext_vector_type(4)));
typedef float floatx4 __attribute__((ext_vector_type(4)));

// W (rows x K) -> 2 scaled f16 planes (rows x Kp), zero-padded K..Kp.
__global__ __launch_bounds__(256) void split_w(const float* __restrict__ W,
                                               f16_t* __restrict__ P,
                                               long plane, int K, int Kp,
                                               float sc) {
  int k4 = (blockIdx.x * 256 + threadIdx.x) * 4;
  if (k4 >= Kp) return;
  long r = blockIdx.y;
  float4 v = (k4 < K) ? *(const float4*)(W + r * (long)K + k4)
                      : float4{0.f, 0.f, 0.f, 0.f};
  float t[4] = {v.x * sc, v.y * sc, v.z * sc, v.w * sc};
  f16x4 a, b;
  #pragma unroll
  for (int e = 0; e < 4; ++e) {
    f16_t h0 = (f16_t)t[e];
    a[e] = h0;
    b[e] = (f16_t)((t[e] - (float)h0) * 4096.f);
  }
  long o = r * (long)Kp + k4;
  *(f16x4*)(P + o) = a;
  *(f16x4*)(P + plane + o) = b;
}

// C[r][n]: A row element offset = (r>>8)*sT + (r&255)*sB.
// AF32: A fp32 -> split to 2 f16 planes during LDS commit (48 MFMA/wave/tile).
// else: A f16 spikes, exact (32 MFMA/wave/tile).
template <bool AF32>
__global__ __launch_bounds__(256, 2) void snn_gemm(
    const float* __restrict__ Af, const f16_t* __restrict__ Ab,
    long sT, long sB, const f16_t* __restrict__ Bp, long planeB,
    int Kp, int K, int numT, const float* __restrict__ bias,
    float* __restrict__ C, int N, float s0, float s1) {
  constexpr int APL = AF32 ? 2 : 1;
  constexpr int LDW = 36;  // 72B row stride: frag reads 2-way (free)
  __shared__ f16_t As[APL][128 * LDW];
  __shared__ f16_t Bs[2][128 * LDW];

  const int tid = threadIdx.x;
  const int wave = tid >> 6, lane = tid & 63;
  const int quad = lane >> 4, l16 = lane & 15;
  const int wm = (wave & 1) * 64, wn = (wave >> 1) * 64;
  const long m0 = (long)blockIdx.x * 128;
  const long n0 = (long)blockIdx.y * 128;

  floatx4 acc0[4][4], acc1[4][4];
  #pragma unroll
  for (int i = 0; i < 4; ++i)
    #pragma unroll
    for (int j = 0; j < 4; ++j) {
      acc0[i][j] = (floatx4){0.f, 0.f, 0.f, 0.f};
      acc1[i][j] = (floatx4){0.f, 0.f, 0.f, 0.f};
    }

  // staging: chunk c = p*256+tid -> tile row c>>2, k-offset (c&3)*8 (16B)
  float4 xv[2][2];
  f16x8 av[2];
  f16x8 bv[2][2];

  auto prefetch = [&](int kt) {
    const int kb = kt * 32;
    #pragma unroll
    for (int p = 0; p < 2; ++p) {
      const int c = p * 256 + tid;
      const long r = m0 + (c >> 2);
      const int k0 = kb + (c & 3) * 8;
      if constexpr (AF32) {
        const float* xr = Af + (r >> 8) * sT + (r & 255) * sB + k0;
        const bool in = (k0 + 8 <= K);
        const float4 z = {0.f, 0.f, 0.f, 0.f};
        xv[p][0] = in ? *(const float4*)xr : z;
        xv[p][1] = in ? *(const float4*)(xr + 4) : z;
      } else {
        av[p] = *(const f16x8*)(Ab + (r >> 8) * sT + (r & 255) * sB + k0);
      }
      #pragma unroll
      for (int q = 0; q < 2; ++q)
        bv[q][p] = *(const f16x8*)(Bp + q * planeB + (n0 + (c >> 2)) * (long)Kp +
                                   k0);
    }
  };

  auto commit = [&]() {
    #pragma unroll
    for (int p = 0; p < 2; ++p) {
      const int c = p * 256 + tid;
      const int off = (c >> 2) * LDW + (c & 3) * 8;
      if constexpr (AF32) {
        float v[8] = {xv[p][0].x, xv[p][0].y, xv[p][0].z, xv[p][0].w,
                      xv[p][1].x, xv[p][1].y, xv[p][1].z, xv[p][1].w};
        f16x8 h0, h1;
        #pragma unroll
        for (int e = 0; e < 8; ++e) {
          f16_t a = (f16_t)v[e];
          h0[e] = a;
          h1[e] = (f16_t)((v[e] - (float)a) * 4096.f);
        }
        *(f16x8*)(&As[0][off]) = h0;
        *(f16x8*)(&As[1][off]) = h1;
      } else {
        *(f16x8*)(&As[0][off]) = av[p];
      }
      *(f16x8*)(&Bs[0][off]) = bv[0][p];
      *(f16x8*)(&Bs[1][off]) = bv[1][p];
    }
  };

  prefetch(0);
  for (int kt = 0; kt < numT; ++kt) {
    __syncthreads();  // [A] prev tile's frag reads done
    commit();
    const int kn = (kt + 1 < numT) ? kt + 1 : 0;  // harmless reload at end
    prefetch(kn);     // round-3 placement: issue BEFORE [B]
    __syncthreads();  // [B] staging visible

    f16x8 a0[4], b0[4], b1[4];
    #pragma unroll
    for (int i = 0; i < 4; ++i)
      a0[i] = *(const f16x8*)(&As[0][(wm + i * 16 + l16) * LDW + quad * 8]);
    #pragma unroll
    for (int j = 0; j < 4; ++j) {
      b0[j] = *(const f16x8*)(&Bs[0][(wn + j * 16 + l16) * LDW + quad * 8]);
      b1[j] = *(const f16x8*)(&Bs[1][(wn + j * 16 + l16) * LDW + quad * 8]);
    }
    #pragma unroll
    for (int i = 0; i < 4; ++i)
      #pragma unroll
      for (int j = 0; j < 4; ++j)
        acc0[i][j] = __builtin_amdgcn_mfma_f32_16x16x32_f16(a0[i], b0[j],
                                                            acc0[i][j], 0, 0, 0);
    #pragma unroll
    for (int i = 0; i < 4; ++i)
      #pragma unroll
      for (int j = 0; j < 4; ++j)
        acc1[i][j] = __builtin_amdgcn_mfma_f32_16x16x32_f16(a0[i], b1[j],
                                                            acc1[i][j], 0, 0, 0);
    if constexpr (AF32) {
      #pragma unroll
      for (int i = 0; i < 4; ++i) {
        f16x8 a1 = *(const f16x8*)(&As[1][(wm + i * 16 + l16) * LDW + quad * 8]);
        #pragma unroll
        for (int j = 0; j < 4; ++j)
          acc1[i][j] = __builtin_amdgcn_mfma_f32_16x16x32_f16(
              a1, b0[j], acc1[i][j], 0, 0, 0);
      }
    }
  }

  // epilogue: C/D layout col=lane&15, row=quad*4+reg
  #pragma unroll
  for (int j = 0; j < 4; ++j) {
    const long col = n0 + wn + j * 16 + l16;
    const float bvv = bias[col];
    #pragma unroll
    for (int i = 0; i < 4; ++i) {
      const long row0 = m0 + wm + i * 16 + quad * 4;
      #pragma unroll
      for (int g = 0; g < 4; ++g)
        C[(row0 + g) * (long)N + col] =
            acc0[i][j][g] * s0 + acc1[i][j][g] * s1 + bvv;
    }
  }
}

// LIF scan: fp32 currents in, f16 spikes {0,1} out (exact).
__global__ __launch_bounds__(256) void lif_scan_f16(const float* __restrict__ I,
                                                    f16_t* __restrict__ S) {
  int idx = blockIdx.x * 256 + threadIdx.x;
  float v = 0.f, cur = 0.f;
  #pragma unroll
  for (int t = 0; t < TT; ++t) {
    float inp = I[(long)t * (TB * TH) + idx];
    float vd = fmaf(0.05f, cur - v, v);
    float id = cur - 0.2f * cur;
    float s = (vd > 1.0f) ? 1.0f : 0.f;
    v = (1.0f - s) * vd;
    cur = id + inp;
    S[(long)t * (TB * TH) + idx] = (f16_t)s;
  }
}

// GEMM3: one wave per row; I3[r][o] = S2[r][:] . Wout[o][:] + bout[o]
__global__ __launch_bounds__(256) void gemm3_kernel(
    const f16_t* __restrict__ S2, const float* __restrict__ Wout,
    const float* __restrict__ bout, float* __restrict__ I3) {
  int wv = (blockIdx.x * 256 + threadIdx.x) >> 6;
  int lane = threadIdx.x & 63;
  if (wv >= TM) return;
  const f16_t* srow = S2 + (long)wv * TH;
  float acc[TOUT];
  #pragma unroll
  for (int o = 0; o < TOUT; ++o) acc[o] = 0.f;
  const int k0 = lane * 16;  // 64 lanes x 16 = 1024 = TH
  f16x8 sa = *(const f16x8*)(srow + k0);
  f16x8 sb = *(const f16x8*)(srow + k0 + 8);
  #pragma unroll
  for (int e = 0; e < 8; ++e) {
    float u = (float)sa[e], w = (float)sb[e];
    #pragma unroll
    for (int o = 0; o < TOUT; ++o) {
      acc[o] = fmaf(u, Wout[o * TH + k0 + e], acc[o]);
      acc[o] = fmaf(w, Wout[o * TH + k0 + 8 + e], acc[o]);
    }
  }
  #pragma unroll
  for (int off = 32; off > 0; off >>= 1)
    #pragma unroll
    for (int o = 0; o < TOUT; ++o) acc[o] += __shfl_down(acc[o], off, 64);
  if (lane == 0) {
    #pragma unroll
    for (int o = 0; o < TOUT; ++o) I3[(long)wv * TOUT + o] = acc[o] + bout[o];
  }
}

__global__ __launch_bounds__(256) void scan_out(const float* __restrict__ I3,
                                                float* __restrict__ out) {
  int idx = blockIdx.x * blockDim.x + threadIdx.x;
  if (idx >= TB * TOUT) return;
  float v = 0.f, cur = 0.f, cnt = 0.f;
  #pragma unroll
  for (int t = 0; t < TT; ++t) {
    float inp = I3[(long)t * (TB * TOUT) + idx];
    float vd = fmaf(0.05f, cur - v, v);
    float id = cur - 0.2f * cur;
    float s = (vd > 1.0f) ? 1.0f : 0.f;
    v = (1.0f - s) * vd;
    cur = id + inp;
    cnt += s;
  }
  out[idx] = cnt;
}

extern "C" void kernel_launch(void* const* d_in, const int* in_sizes, int n_in,
                              void* d_out, int out_size, void* d_ws,
                              size_t ws_size, hipStream_t stream) {
  const float* x    = (const float*)d_in[0];  // (256,32,2312)
  const float* W1   = (const float*)d_in[1];  // (1024,2312)
  const float* b1   = (const float*)d_in[2];
  const float* W2   = (const float*)d_in[3];  // (1024,1024)
  const float* b2   = (const float*)d_in[4];
  const float* Wout = (const float*)d_in[5];  // (10,1024)
  const float* bout = (const float*)d_in[6];

  // ws: W1p 9.70MB | W2p 4.19MB | bufI 33.55MB | S 16.78MB | buf3 0.33MB
  f16_t* W1p  = (f16_t*)d_ws;
  f16_t* W2p  = W1p + 2L * TH * KP1;
  float* bufI = (float*)(W2p + 2L * TH * TH);
  f16_t* S    = (f16_t*)(bufI + (long)TM * TH);
  float* buf3 = (float*)(S + (long)TM * TH);

  split_w<<<dim3((KP1 / 4 + 255) / 256, TH), 256, 0, stream>>>(
      W1, W1p, (long)TH * KP1, TIN, KP1, 64.f);
  split_w<<<dim3(1, TH), 256, 0, stream>>>(
      W2, W2p, (long)TH * TH, TH, TH, 32.f);

  // GEMM1: row r=(t,b): x offset = (r&255)*(32*2312) + (r>>8)*2312
  snn_gemm<true><<<dim3(TM / 128, TH / 128), 256, 0, stream>>>(
      x, nullptr, (long)TIN, (long)TT * TIN, W1p, (long)TH * KP1, KP1, TIN,
      KP1 / 32, b1, bufI, TH, 1.f / 64.f, 1.f / 262144.f);

  lif_scan_f16<<<(TB * TH) / 256, 256, 0, stream>>>(bufI, S);

  // GEMM2: S row-major [8192][1024]
  snn_gemm<false><<<dim3(TM / 128, TH / 128), 256, 0, stream>>>(
      nullptr, S, (long)TB * TH, (long)TH, W2p, (long)TH * TH, TH, TH,
      TH / 32, b2, bufI, TH, 1.f / 32.f, 1.f / 131072.f);

  lif_scan_f16<<<(TB * TH) / 256, 256, 0, stream>>>(bufI, S);

  gemm3_kernel<<<(TM * 64) / 256, 256, 0, stream>>>(S, Wout, bout, buf3);

  scan_out<<<(TB * TOUT + 255) / 256, 256, 0, stream>>>(buf3, (float*)d_out);
}